// Round 11
// baseline (122.424 us; speedup 1.0000x reference)
//
#include <hip/hip_runtime.h>
#include <math.h>

#define SS 2048
#define DIN 2112
#define TOK 16            // tokens per block
#define NBLK 1024
#define NTHR 256          // 4 waves
#define XSTR 68           // xs row stride (fp32)
#define CSTR 132          // C partial row stride (fp32)
#define BFRAG_ELEMS (66 * 8 * 64 * 8)   // 270336 f16
#define LOG2E 1.4426950408889634f
#define INV2PI 0.15915494309189535f

// ws float-offsets (after 270336 f16 = 135168 floats of Bfrag)
#define OFF_WP 135168     // [256]  log2e-folded WP[4][64]
#define OFF_CP 135424     // [4]
#define OFF_FV 135680     // 1024 halves: fp16 fm*fs
#define OFF_PH 136192     // 1024 halves: fp16 phase/2pi
#define OFF_MX 136704     // [128]  per-d {max,min} of fp16-rounded fv

typedef __attribute__((ext_vector_type(4))) float f32x4;
typedef __attribute__((ext_vector_type(8))) _Float16 f16x8;
typedef __attribute__((ext_vector_type(2))) __fp16 fp16v2;

__device__ __forceinline__ unsigned pkh(float a, float b) {
#if __has_builtin(__builtin_amdgcn_cvt_pkrtz)
    union { fp16v2 h; unsigned u; } r;
    r.h = __builtin_amdgcn_cvt_pkrtz(a, b);     // v_cvt_pkrtz_f16_f32
    return r.u;
#else
    union { _Float16 h[2]; unsigned u; } r;
    r.h[0] = (_Float16)a; r.h[1] = (_Float16)b;
    return r.u;
#endif
}

#if __has_builtin(__builtin_amdgcn_exp2f)
#define EXP2(x) __builtin_amdgcn_exp2f(x)
#else
#define EXP2(x) exp2f(x)
#endif
#if __has_builtin(__builtin_amdgcn_rcpf)
#define RCP(x) __builtin_amdgcn_rcpf(x)
#else
#define RCP(x) (1.0f / (x))
#endif
#if __has_builtin(__builtin_amdgcn_sinf)
#define SINR(x) __builtin_amdgcn_sinf(x)   // sin(2*pi*x), revolutions (verified R3-R10)
#else
#define SINR(x) __sinf(6.283185307179586f * (x))
#endif

// ---------------- precompute (unchanged from R8-R10) ----------------
__global__ __launch_bounds__(256) void aff_pre(
    const float* __restrict__ Wq, const float* __restrict__ bq,
    const float* __restrict__ Wk1,
    const float* __restrict__ Wqi, const float* __restrict__ bqi,
    const float* __restrict__ Wki,
    const float* __restrict__ Wg, const float* __restrict__ Wp,
    const float* __restrict__ fm, const float* __restrict__ fs,
    const float* __restrict__ phase,
    float* __restrict__ ws)
{
    _Float16* Bf = (_Float16*)ws;
    const int tid = threadIdx.x;
    const int gid = blockIdx.x * 256 + tid;   // < 270336 exactly

    {
        int j  = gid & 7;
        int q  = (gid >> 3) & 3;
        int nl = (gid >> 5) & 15;
        int nt = (gid >> 9) & 7;
        int kt = gid >> 12;
        int k = kt * 32 + q * 8 + j;
        int n = nt * 16 + nl;
        float s = (n < 64) ? Wg[(size_t)n * DIN + k] : Wp[(size_t)(n - 64) * DIN + k];
        int dst = ((kt * 8 + nt) * 64 + q * 16 + nl) * 8 + j;
        Bf[dst] = (_Float16)s;
    }

    if (blockIdx.x == 0) {
        float* WP = ws + OFF_WP;
        float* cP = ws + OFF_CP;
        unsigned* fvh = (unsigned*)(ws + OFF_FV);
        unsigned* phh = (unsigned*)(ws + OFF_PH);
        float* mxg = ws + OFF_MX;

        {
            float4 a = ((const float4*)fm)[tid];
            float4 b = ((const float4*)fs)[tid];
            fvh[tid * 2]     = pkh(a.x * b.x, a.y * b.y);
            fvh[tid * 2 + 1] = pkh(a.z * b.z, a.w * b.w);
            float4 p = ((const float4*)phase)[tid];
            phh[tid * 2]     = pkh(p.x * INV2PI, p.y * INV2PI);
            phh[tid * 2 + 1] = pkh(p.z * INV2PI, p.w * INV2PI);
        }
        if (tid < 64) {
            float mx = -1e30f, mn = 1e30f;
            #pragma unroll
            for (int f = 0; f < 16; ++f) {
                float v = (float)(_Float16)(fm[tid * 16 + f] * fs[tid * 16 + f]);
                mx = fmaxf(mx, v); mn = fminf(mn, v);
            }
            mxg[tid * 2] = mx; mxg[tid * 2 + 1] = mn;
        }

        __shared__ float u[32];
        if (tid < 32) {
            float s = 0.f;
            #pragma unroll
            for (int a = 0; a < 32; ++a) s += Wki[tid * 32 + a] * Wk1[a];
            u[tid] = s;
        }
        __syncthreads();
        {
            const int h = tid >> 6;
            const int d = tid & 63;
            float s = 0.f;
            for (int j = 0; j < 8; ++j) {
                int e = h * 8 + j;
                float wc = 0.f;
                #pragma unroll
                for (int a = 0; a < 32; ++a) wc += Wqi[e * 32 + a] * Wq[a * 64 + d];
                s += u[e] * wc;
            }
            WP[h * 64 + d] = s * 0.35355339059327373f * LOG2E;
            if (d == 0) {
                float sc = 0.f;
                for (int j = 0; j < 8; ++j) {
                    int e = h * 8 + j;
                    float bcv = bqi[e];
                    #pragma unroll
                    for (int a = 0; a < 32; ++a) bcv += Wqi[e * 32 + a] * bq[a];
                    sc += u[e] * bcv;
                }
                cP[h] = sc * 0.35355339059327373f * LOG2E;
            }
        }
    }
}

// ---------------- main fused kernel: K split across waves, barrier-free main loop ----------------
// 16 tokens/block, 4 waves. Wave w owns K-slice: x-tile w (w<2) + fourier d in [w*16, w*16+16).
// Each lane builds ITS OWN A-operand: lane = (m=lane&15, lq=lane>>4); for one d,
// lq0: sin f0-7 (k0-7), lq1: sin f8-15, lq2: cos f0-7 (k16-23), lq3: cos f8-15 —
// cos = sin(x + 0.25 rev), so no divergence. Softmax split: lane computes exps for 2 heads
// (pair = lane>>5) x its f-half; combine via shfl_xor(16)=f-half, shfl_xor(32)=head-pair.
// Partial C per wave over all 8 n-tiles; summed via LDS at the end (single barrier).
__global__ __launch_bounds__(NTHR, 3) void aff_main(
    const float* __restrict__ x,
    const float* __restrict__ ws_c,
    const float* __restrict__ bg, const float* __restrict__ bp,
    float* __restrict__ out)
{
    __shared__ __align__(16) float xs[TOK * XSTR];           // 4352 B
    __shared__ __align__(16) float Cpart[4 * TOK * CSTR];    // 33792 B
    __shared__ __align__(16) float Pl[TOK * 4];              // 256 B
    __shared__ __align__(16) _Float16 fvh[1024];             // 2048 B
    __shared__ __align__(16) _Float16 phh[1024];             // 2048 B
    __shared__ __align__(16) float mxs[128];                 // 512 B
                                                             // total 43008 B -> 3 blocks/CU

    const f16x8* Bv = (const f16x8*)ws_c;
    const float* WP  = ws_c + OFF_WP;
    const float* cP  = ws_c + OFF_CP;
    const float* mxg = ws_c + OFF_MX;

    const int tid  = threadIdx.x;
    const int lane = tid & 63;
    const int w    = tid >> 6;          // wave 0..3 = K-slice
    const int t0   = blockIdx.x * TOK;
    const int lm   = lane & 15;         // token / m-row
    const int lq   = lane >> 4;         // k-octet
    const int fsel = lq & 1;            // f-half
    const int hp   = lq >> 1;           // head-pair (also sin/cos selector)
    const float qoff = hp ? 0.25f : 0.0f;   // cos = sin(x + 1/4 rev)

    // ---- stage: fv/ph (fp16), minmax, x -> LDS ----
    {
        uint2 fv2 = ((const uint2*)(ws_c + OFF_FV))[tid];
        uint2 ph2 = ((const uint2*)(ws_c + OFF_PH))[tid];
        ((uint2*)fvh)[tid] = fv2;
        ((uint2*)phh)[tid] = ph2;
    }
    if (tid < 32) ((float4*)mxs)[tid] = ((const float4*)mxg)[tid];
    {
        int t = tid >> 4, j4 = (tid & 15) * 4;
        float4 xv = *(const float4*)(x + (size_t)(t0 + t) * 64 + j4);
        *(float4*)(xs + t * XSTR + j4) = xv;
    }
    __syncthreads();

    // ---- P (exp2-domain) on waves 2,3 (overlaps with waves 0/1's x-tile below) ----
    if (tid >= 128) {
        int t2 = tid - 128;
        int t = t2 & 15, dh = (t2 >> 4) & 1, h = t2 >> 5;
        float acc = 0.f;
        const float* wp = WP + h * 64 + dh * 32;
        const float* xr = xs + t * XSTR + dh * 32;
        #pragma unroll 8
        for (int d = 0; d < 32; ++d) acc = fmaf(wp[d], xr[d], acc);
        acc += __shfl_xor(acc, 16);
        if (dh == 0) Pl[t * 4 + h] = acc + cP[h];
    }

    f32x4 acc[8] = {};
    f16x8 B0[8], B1[8];
    auto loadB = [&](int kt, f16x8* Bb) {
        const f16x8* p = Bv + (size_t)kt * 512 + lane;
        #pragma unroll
        for (int nt = 0; nt < 8; ++nt) Bb[nt] = p[nt * 64];
    };

    const int dbase = w * 16;

    // ---- x-tile for waves 0,1 (k-tiles 0,1); waves 2,3 just prefetch ----
    if (w < 2) {
        loadB(w, B0);
        union { unsigned u[4]; f16x8 v; } ax;
        const float* xr = xs + lm * XSTR + w * 32 + lq * 8;
        ax.u[0] = pkh(xr[0], xr[1]); ax.u[1] = pkh(xr[2], xr[3]);
        ax.u[2] = pkh(xr[4], xr[5]); ax.u[3] = pkh(xr[6], xr[7]);
        loadB(2 + dbase, B1);
        #pragma unroll
        for (int nt = 0; nt < 8; ++nt)
            acc[nt] = __builtin_amdgcn_mfma_f32_16x16x32_f16(ax.v, B0[nt], acc[nt], 0, 0, 0);
    } else {
        loadB(2 + dbase, B1);
    }
    __syncthreads();   // Pl ready

    const float P0 = Pl[lm * 4 + hp * 2];
    const float P1 = Pl[lm * 4 + hp * 2 + 1];
    const float w2 = (float)((t0 + lm) & (SS - 1)) * (1.0f / 2047.0f);  // revolutions

    auto build = [&](int d) -> f16x8 {
        union { uint4 q; _Float16 h[8]; } fu, pu;
        fu.q = *(const uint4*)(fvh + d * 16 + fsel * 8);
        pu.q = *(const uint4*)(phh + d * 16 + fsel * 8);
        const float mxv = mxs[d * 2], mnv = mxs[d * 2 + 1];
        float fl[8], prq[8];
        #pragma unroll
        for (int j = 0; j < 8; ++j) { fl[j] = (float)fu.h[j]; prq[j] = (float)pu.h[j] + qoff; }
        const float m0 = fmaxf(mxv * P0, mnv * P0);   // exact row max (monotone in f)
        const float m1 = fmaxf(mxv * P1, mnv * P1);
        float e0[8], e1[8], s0 = 0.f, s1 = 0.f;
        #pragma unroll
        for (int j = 0; j < 8; ++j) { e0[j] = EXP2(fmaf(fl[j], P0, -m0)); s0 += e0[j]; }
        #pragma unroll
        for (int j = 0; j < 8; ++j) { e1[j] = EXP2(fmaf(fl[j], P1, -m1)); s1 += e1[j]; }
        const float z0 = s0 + __shfl_xor(s0, 16);     // other f-half, same heads
        const float z1 = s1 + __shfl_xor(s1, 16);
        const float i0 = 0.25f * RCP(z0), i1 = 0.25f * RCP(z1);
        union { unsigned u[4]; f16x8 v; } r;
        #pragma unroll
        for (int jp = 0; jp < 4; ++jp) {
            const int j0 = 2 * jp, j1 = 2 * jp + 1;
            float a0 = fmaf(e1[j0], i1, e0[j0] * i0);   // this head-pair's contribution
            float a1 = fmaf(e1[j1], i1, e0[j1] * i0);
            a0 += __shfl_xor(a0, 32);                   // + other head-pair (same f, same type slot)
            a1 += __shfl_xor(a1, 32);
            const float X0 = fmaf(w2, fl[j0], prq[j0]);
            const float X1 = fmaf(w2, fl[j1], prq[j1]);
            r.u[jp] = pkh(a0 * SINR(X0), a1 * SINR(X1));
        }
        return r.v;
    };

    // ---- barrier-free main loop: 16 fourier k-tiles, double-buffered B in registers ----
    #pragma unroll
    for (int i = 0; i < 16; ++i) {
        f16x8* cur = (i & 1) ? B0 : B1;
        f16x8* nxt = (i & 1) ? B1 : B0;
        f16x8 a = build(dbase + i);              // ~600 cyc: covers cur's in-flight loads
        if (i < 15) loadB(2 + dbase + i + 1, nxt);
        #pragma unroll
        for (int nt = 0; nt < 8; ++nt)
            acc[nt] = __builtin_amdgcn_mfma_f32_16x16x32_f16(a, cur[nt], acc[nt], 0, 0, 0);
    }

    // ---- epilogue: 4 partials -> LDS, single barrier, sum + activation + residual ----
    {
        float* Cw = Cpart + w * TOK * CSTR;
        #pragma unroll
        for (int nt = 0; nt < 8; ++nt)
            #pragma unroll
            for (int r = 0; r < 4; ++r)
                Cw[(lq * 4 + r) * CSTR + nt * 16 + lm] = acc[nt][r];
    }
    __syncthreads();
    {
        int t = tid >> 4, o0 = (tid & 15) * 4;
        float4 g4 = make_float4(0.f, 0.f, 0.f, 0.f), p4 = g4;
        #pragma unroll
        for (int ww = 0; ww < 4; ++ww) {
            const float* Cw = Cpart + ww * TOK * CSTR + t * CSTR;
            float4 g = *(const float4*)(Cw + o0);
            float4 p = *(const float4*)(Cw + 64 + o0);
            g4.x += g.x; g4.y += g.y; g4.z += g.z; g4.w += g.w;
            p4.x += p.x; p4.y += p.y; p4.z += p.z; p4.w += p.w;
        }
        float4 bg4 = *(const float4*)(bg + o0);
        float4 bp4 = *(const float4*)(bp + o0);
        float4 xr = *(float4*)(xs + t * XSTR + o0);
        float4 o;
        { float g = g4.x + bg4.x, p = p4.x + bp4.x;
          o.x = fmaf(p * RCP(1.f + EXP2(-g * LOG2E)), RCP(1.f + EXP2(-p * LOG2E)), xr.x); }
        { float g = g4.y + bg4.y, p = p4.y + bp4.y;
          o.y = fmaf(p * RCP(1.f + EXP2(-g * LOG2E)), RCP(1.f + EXP2(-p * LOG2E)), xr.y); }
        { float g = g4.z + bg4.z, p = p4.z + bp4.z;
          o.z = fmaf(p * RCP(1.f + EXP2(-g * LOG2E)), RCP(1.f + EXP2(-p * LOG2E)), xr.z); }
        { float g = g4.w + bg4.w, p = p4.w + bp4.w;
          o.w = fmaf(p * RCP(1.f + EXP2(-g * LOG2E)), RCP(1.f + EXP2(-p * LOG2E)), xr.w); }
        *(float4*)(out + (size_t)(t0 + t) * 64 + o0) = o;
    }
}

extern "C" void kernel_launch(void* const* d_in, const int* in_sizes, int n_in,
                              void* d_out, int out_size, void* d_ws, size_t ws_size,
                              hipStream_t stream) {
    (void)in_sizes; (void)n_in; (void)out_size; (void)ws_size;
    const float* x    = (const float*)d_in[0];
    const float* fm   = (const float*)d_in[1];
    const float* phs  = (const float*)d_in[2];
    const float* fs   = (const float*)d_in[3];
    const float* Wq   = (const float*)d_in[4];
    const float* bq   = (const float*)d_in[5];
    const float* Wk1  = (const float*)d_in[6];
    // d_in[7] = bk1: cancels in softmax
    const float* Wqi  = (const float*)d_in[8];
    const float* bqi  = (const float*)d_in[9];
    const float* Wki  = (const float*)d_in[10];
    // d_in[11] = bki: cancels in softmax
    const float* Wg   = (const float*)d_in[12];
    const float* bg   = (const float*)d_in[13];
    const float* Wp   = (const float*)d_in[14];
    const float* bp   = (const float*)d_in[15];
    float* out = (float*)d_out;
    float* ws  = (float*)d_ws;

    aff_pre<<<BFRAG_ELEMS / 256, 256, 0, stream>>>(Wq, bq, Wk1, Wqi, bqi, Wki, Wg, Wp,
                                                   fm, fs, phs, ws);
    aff_main<<<NBLK, NTHR, 0, stream>>>(x, (const float*)ws, bg, bp, out);
}

// Round 12
// 119.708 us; speedup vs baseline: 1.0227x; 1.0227x over previous
//
#include <hip/hip_runtime.h>
#include <math.h>

#define SS 2048
#define DIN 2112
#define TOK 16            // tokens per block
#define NBLK 1024
#define NTHR 256          // 4 waves
#define XSTR 68           // xs row stride (fp32)
#define CSTR 132          // C partial row stride (fp32)
#define BFRAG_ELEMS (66 * 8 * 64 * 8)   // 270336 f16
#define LOG2E 1.4426950408889634f
#define INV2PI 0.15915494309189535f

// ws float-offsets (after 270336 f16 = 135168 floats of Bfrag)
#define OFF_WP 135168     // [256]  log2e-folded WP[4][64]
#define OFF_CP 135424     // [4]
#define OFF_FV 135680     // 1024 halves: fp16 fm*fs
#define OFF_PH 136192     // 1024 halves: fp16 phase/2pi
#define OFF_MX 136704     // [128]  per-d {max,min} of fp16-rounded fv

typedef __attribute__((ext_vector_type(4))) float f32x4;
typedef __attribute__((ext_vector_type(8))) _Float16 f16x8;
typedef __attribute__((ext_vector_type(2))) __fp16 fp16v2;

__device__ __forceinline__ unsigned pkh(float a, float b) {
#if __has_builtin(__builtin_amdgcn_cvt_pkrtz)
    union { fp16v2 h; unsigned u; } r;
    r.h = __builtin_amdgcn_cvt_pkrtz(a, b);     // v_cvt_pkrtz_f16_f32
    return r.u;
#else
    union { _Float16 h[2]; unsigned u; } r;
    r.h[0] = (_Float16)a; r.h[1] = (_Float16)b;
    return r.u;
#endif
}

#if __has_builtin(__builtin_amdgcn_exp2f)
#define EXP2(x) __builtin_amdgcn_exp2f(x)
#else
#define EXP2(x) exp2f(x)
#endif
#if __has_builtin(__builtin_amdgcn_rcpf)
#define RCP(x) __builtin_amdgcn_rcpf(x)
#else
#define RCP(x) (1.0f / (x))
#endif
#if __has_builtin(__builtin_amdgcn_sinf)
#define SINR(x) __builtin_amdgcn_sinf(x)   // sin(2*pi*x), revolutions (verified R3-R11)
#else
#define SINR(x) __sinf(6.283185307179586f * (x))
#endif

// ---------------- precompute (unchanged from R8-R11) ----------------
__global__ __launch_bounds__(256) void aff_pre(
    const float* __restrict__ Wq, const float* __restrict__ bq,
    const float* __restrict__ Wk1,
    const float* __restrict__ Wqi, const float* __restrict__ bqi,
    const float* __restrict__ Wki,
    const float* __restrict__ Wg, const float* __restrict__ Wp,
    const float* __restrict__ fm, const float* __restrict__ fs,
    const float* __restrict__ phase,
    float* __restrict__ ws)
{
    _Float16* Bf = (_Float16*)ws;
    const int tid = threadIdx.x;
    const int gid = blockIdx.x * 256 + tid;   // < 270336 exactly

    {
        int j  = gid & 7;
        int q  = (gid >> 3) & 3;
        int nl = (gid >> 5) & 15;
        int nt = (gid >> 9) & 7;
        int kt = gid >> 12;
        int k = kt * 32 + q * 8 + j;
        int n = nt * 16 + nl;
        float s = (n < 64) ? Wg[(size_t)n * DIN + k] : Wp[(size_t)(n - 64) * DIN + k];
        int dst = ((kt * 8 + nt) * 64 + q * 16 + nl) * 8 + j;
        Bf[dst] = (_Float16)s;
    }

    if (blockIdx.x == 0) {
        float* WP = ws + OFF_WP;
        float* cP = ws + OFF_CP;
        unsigned* fvh = (unsigned*)(ws + OFF_FV);
        unsigned* phh = (unsigned*)(ws + OFF_PH);
        float* mxg = ws + OFF_MX;

        {
            float4 a = ((const float4*)fm)[tid];
            float4 b = ((const float4*)fs)[tid];
            fvh[tid * 2]     = pkh(a.x * b.x, a.y * b.y);
            fvh[tid * 2 + 1] = pkh(a.z * b.z, a.w * b.w);
            float4 p = ((const float4*)phase)[tid];
            phh[tid * 2]     = pkh(p.x * INV2PI, p.y * INV2PI);
            phh[tid * 2 + 1] = pkh(p.z * INV2PI, p.w * INV2PI);
        }
        if (tid < 64) {
            float mx = -1e30f, mn = 1e30f;
            #pragma unroll
            for (int f = 0; f < 16; ++f) {
                float v = (float)(_Float16)(fm[tid * 16 + f] * fs[tid * 16 + f]);
                mx = fmaxf(mx, v); mn = fminf(mn, v);
            }
            mxg[tid * 2] = mx; mxg[tid * 2 + 1] = mn;
        }

        __shared__ float u[32];
        if (tid < 32) {
            float s = 0.f;
            #pragma unroll
            for (int a = 0; a < 32; ++a) s += Wki[tid * 32 + a] * Wk1[a];
            u[tid] = s;
        }
        __syncthreads();
        {
            const int h = tid >> 6;
            const int d = tid & 63;
            float s = 0.f;
            for (int j = 0; j < 8; ++j) {
                int e = h * 8 + j;
                float wc = 0.f;
                #pragma unroll
                for (int a = 0; a < 32; ++a) wc += Wqi[e * 32 + a] * Wq[a * 64 + d];
                s += u[e] * wc;
            }
            WP[h * 64 + d] = s * 0.35355339059327373f * LOG2E;
            if (d == 0) {
                float sc = 0.f;
                for (int j = 0; j < 8; ++j) {
                    int e = h * 8 + j;
                    float bcv = bqi[e];
                    #pragma unroll
                    for (int a = 0; a < 32; ++a) bcv += Wqi[e * 32 + a] * bq[a];
                    sc += u[e] * bcv;
                }
                cP[h] = sc * 0.35355339059327373f * LOG2E;
            }
        }
    }
}

// ---------------- main fused kernel: barrier-free K-split, single-buffer B, compact loop ----------------
// 16 tokens/block, 4 waves. Wave w owns K-slice: x-tile w (w<2) + fourier d in [w*16, w*16+16).
// Lane builds its own A-operand (m=lane&15, lq=lane>>4): lq0 sin f0-7, lq1 sin f8-15,
// lq2 cos f0-7, lq3 cos f8-15 (cos = sin(x+0.25rev)). Softmax: lane does 2 heads x f-half;
// combine shfl_xor(16)=f-half, shfl_xor(32)=head-pair. B single-buffered: loads for iter i+1
// issued after iter i's MFMAs, in flight across build(i+1) (~600 cyc >> 200-cyc L2).
__global__ __launch_bounds__(NTHR, 3) void aff_main(
    const float* __restrict__ x,
    const float* __restrict__ ws_c,
    const float* __restrict__ bg, const float* __restrict__ bp,
    float* __restrict__ out)
{
    __shared__ __align__(16) float xs[TOK * XSTR];           // 4352 B
    __shared__ __align__(16) float Cpart[4 * TOK * CSTR];    // 33792 B
    __shared__ __align__(16) float Pl[TOK * 4];              // 256 B
    __shared__ __align__(16) _Float16 fvh[1024];             // 2048 B
    __shared__ __align__(16) _Float16 phh[1024];             // 2048 B
    __shared__ __align__(16) float mxs[128];                 // 512 B

    const f16x8* Bv = (const f16x8*)ws_c;
    const float* WP  = ws_c + OFF_WP;
    const float* cP  = ws_c + OFF_CP;
    const float* mxg = ws_c + OFF_MX;

    const int tid  = threadIdx.x;
    const int lane = tid & 63;
    const int w    = tid >> 6;          // wave 0..3 = K-slice
    const int t0   = blockIdx.x * TOK;
    const int lm   = lane & 15;         // token / m-row
    const int lq   = lane >> 4;         // k-octet
    const int fsel = lq & 1;            // f-half
    const int hp   = lq >> 1;           // head-pair (also sin/cos selector)
    const float qoff = hp ? 0.25f : 0.0f;   // cos = sin(x + 1/4 rev)

    // ---- stage: fv/ph (fp16), minmax, x -> LDS ----
    {
        uint2 fv2 = ((const uint2*)(ws_c + OFF_FV))[tid];
        uint2 ph2 = ((const uint2*)(ws_c + OFF_PH))[tid];
        ((uint2*)fvh)[tid] = fv2;
        ((uint2*)phh)[tid] = ph2;
    }
    if (tid < 32) ((float4*)mxs)[tid] = ((const float4*)mxg)[tid];
    {
        int t = tid >> 4, j4 = (tid & 15) * 4;
        float4 xv = *(const float4*)(x + (size_t)(t0 + t) * 64 + j4);
        *(float4*)(xs + t * XSTR + j4) = xv;
    }
    __syncthreads();

    f32x4 acc[8] = {};
    f16x8 B[8];
    auto loadB = [&](int kt) {
        const f16x8* p = Bv + (size_t)kt * 512 + lane;
        #pragma unroll
        for (int nt = 0; nt < 8; ++nt) B[nt] = p[nt * 64];
    };

    const int dbase = w * 16;

    // ---- waves 0,1: x-tile (kt w). waves 2,3: P compute. Then all prefetch first fourier kt ----
    if (w < 2) {
        loadB(w);
        union { unsigned u[4]; f16x8 v; } ax;
        const float* xr = xs + lm * XSTR + w * 32 + lq * 8;
        ax.u[0] = pkh(xr[0], xr[1]); ax.u[1] = pkh(xr[2], xr[3]);
        ax.u[2] = pkh(xr[4], xr[5]); ax.u[3] = pkh(xr[6], xr[7]);
        #pragma unroll
        for (int nt = 0; nt < 8; ++nt)
            acc[nt] = __builtin_amdgcn_mfma_f32_16x16x32_f16(ax.v, B[nt], acc[nt], 0, 0, 0);
    } else {
        int t2 = tid - 128;
        int t = t2 & 15, dh = (t2 >> 4) & 1, h = t2 >> 5;
        float pacc = 0.f;
        const float* wp = WP + h * 64 + dh * 32;
        const float* xr = xs + t * XSTR + dh * 32;
        #pragma unroll 8
        for (int d = 0; d < 32; ++d) pacc = fmaf(wp[d], xr[d], pacc);
        pacc += __shfl_xor(pacc, 16);
        if (dh == 0) Pl[t * 4 + h] = pacc + cP[h];
    }
    loadB(2 + dbase);
    __syncthreads();   // Pl ready

    const float P0 = Pl[lm * 4 + hp * 2];
    const float P1 = Pl[lm * 4 + hp * 2 + 1];
    const float w2 = (float)((t0 + lm) & (SS - 1)) * (1.0f / 2047.0f);  // revolutions

    // ---- barrier-free main loop: 16 fourier k-tiles, compact body (no cross-iter unroll) ----
    #pragma unroll 1
    for (int i = 0; i < 16; ++i) {
        const int d = dbase + i;
        // build this lane's A-operand
        union { uint4 q; _Float16 h[8]; } fu, pu;
        fu.q = *(const uint4*)(fvh + d * 16 + fsel * 8);
        pu.q = *(const uint4*)(phh + d * 16 + fsel * 8);
        const float mxv = mxs[d * 2], mnv = mxs[d * 2 + 1];
        float fl[8];
        #pragma unroll
        for (int j = 0; j < 8; ++j) fl[j] = (float)fu.h[j];
        const float m0 = fmaxf(mxv * P0, mnv * P0);   // exact row max (monotone in f)
        const float m1 = fmaxf(mxv * P1, mnv * P1);
        float e0[8], e1[8], s0 = 0.f, s1 = 0.f;
        #pragma unroll
        for (int j = 0; j < 8; ++j) { e0[j] = EXP2(fmaf(fl[j], P0, -m0)); s0 += e0[j]; }
        #pragma unroll
        for (int j = 0; j < 8; ++j) { e1[j] = EXP2(fmaf(fl[j], P1, -m1)); s1 += e1[j]; }
        const float z0 = s0 + __shfl_xor(s0, 16);     // other f-half, same heads
        const float z1 = s1 + __shfl_xor(s1, 16);
        const float i0 = 0.25f * RCP(z0), i1 = 0.25f * RCP(z1);
        union { unsigned u[4]; f16x8 v; } r;
        #pragma unroll
        for (int jp = 0; jp < 4; ++jp) {
            const int j0 = 2 * jp, j1 = 2 * jp + 1;
            float a0 = fmaf(e1[j0], i1, e0[j0] * i0);   // this head-pair's contribution
            float a1 = fmaf(e1[j1], i1, e0[j1] * i0);
            a0 += __shfl_xor(a0, 32);                   // + other head-pair
            a1 += __shfl_xor(a1, 32);
            const float X0 = fmaf(w2, fl[j0], (float)pu.h[j0] + qoff);
            const float X1 = fmaf(w2, fl[j1], (float)pu.h[j1] + qoff);
            r.u[jp] = pkh(a0 * SINR(X0), a1 * SINR(X1));
        }
        // MFMA on B loaded one iteration ago (in flight across this build)
        #pragma unroll
        for (int nt = 0; nt < 8; ++nt)
            acc[nt] = __builtin_amdgcn_mfma_f32_16x16x32_f16(r.v, B[nt], acc[nt], 0, 0, 0);
        // issue next iteration's B loads (wraps to first kt on last iter; harmless)
        loadB(2 + dbase + ((i + 1) & 15));
    }

    // ---- epilogue: 4 partials -> LDS, single barrier, sum + activation + residual ----
    {
        float* Cw = Cpart + w * TOK * CSTR;
        #pragma unroll
        for (int nt = 0; nt < 8; ++nt)
            #pragma unroll
            for (int r = 0; r < 4; ++r)
                Cw[(lq * 4 + r) * CSTR + nt * 16 + lm] = acc[nt][r];
    }
    __syncthreads();
    {
        int t = tid >> 4, o0 = (tid & 15) * 4;
        float4 g4 = make_float4(0.f, 0.f, 0.f, 0.f), p4 = g4;
        #pragma unroll
        for (int ww = 0; ww < 4; ++ww) {
            const float* Cw = Cpart + ww * TOK * CSTR + t * CSTR;
            float4 g = *(const float4*)(Cw + o0);
            float4 p = *(const float4*)(Cw + 64 + o0);
            g4.x += g.x; g4.y += g.y; g4.z += g.z; g4.w += g.w;
            p4.x += p.x; p4.y += p.y; p4.z += p.z; p4.w += p.w;
        }
        float4 bg4 = *(const float4*)(bg + o0);
        float4 bp4 = *(const float4*)(bp + o0);
        float4 xr = *(float4*)(xs + t * XSTR + o0);
        float4 o;
        { float g = g4.x + bg4.x, p = p4.x + bp4.x;
          o.x = fmaf(p * RCP(1.f + EXP2(-g * LOG2E)), RCP(1.f + EXP2(-p * LOG2E)), xr.x); }
        { float g = g4.y + bg4.y, p = p4.y + bp4.y;
          o.y = fmaf(p * RCP(1.f + EXP2(-g * LOG2E)), RCP(1.f + EXP2(-p * LOG2E)), xr.y); }
        { float g = g4.z + bg4.z, p = p4.z + bp4.z;
          o.z = fmaf(p * RCP(1.f + EXP2(-g * LOG2E)), RCP(1.f + EXP2(-p * LOG2E)), xr.z); }
        { float g = g4.w + bg4.w, p = p4.w + bp4.w;
          o.w = fmaf(p * RCP(1.f + EXP2(-g * LOG2E)), RCP(1.f + EXP2(-p * LOG2E)), xr.w); }
        *(float4*)(out + (size_t)(t0 + t) * 64 + o0) = o;
    }
}

extern "C" void kernel_launch(void* const* d_in, const int* in_sizes, int n_in,
                              void* d_out, int out_size, void* d_ws, size_t ws_size,
                              hipStream_t stream) {
    (void)in_sizes; (void)n_in; (void)out_size; (void)ws_size;
    const float* x    = (const float*)d_in[0];
    const float* fm   = (const float*)d_in[1];
    const float* phs  = (const float*)d_in[2];
    const float* fs   = (const float*)d_in[3];
    const float* Wq   = (const float*)d_in[4];
    const float* bq   = (const float*)d_in[5];
    const float* Wk1  = (const float*)d_in[6];
    // d_in[7] = bk1: cancels in softmax
    const float* Wqi  = (const float*)d_in[8];
    const float* bqi  = (const float*)d_in[9];
    const float* Wki  = (const float*)d_in[10];
    // d_in[11] = bki: cancels in softmax
    const float* Wg   = (const float*)d_in[12];
    const float* bg   = (const float*)d_in[13];
    const float* Wp   = (const float*)d_in[14];
    const float* bp   = (const float*)d_in[15];
    float* out = (float*)d_out;
    float* ws  = (float*)d_ws;

    aff_pre<<<BFRAG_ELEMS / 256, 256, 0, stream>>>(Wq, bq, Wk1, Wqi, bqi, Wki, Wg, Wp,
                                                   fm, fs, phs, ws);
    aff_main<<<NBLK, NTHR, 0, stream>>>(x, (const float*)ws, bg, bp, out);
}

// Round 13
// 117.755 us; speedup vs baseline: 1.0396x; 1.0166x over previous
//
#include <hip/hip_runtime.h>
#include <math.h>

#define SS 2048
#define DIN 2112
#define NKT 66            // K tiles of 32 (kt 0,1 = x; kt 2.. = fourier)
#define TOK 16            // tokens per block
#define NBLK 1024
#define NTHR 256          // 4 waves
#define ASTR 264          // A chunk row stride (f16): 132 dw == 4 mod 32 (quad-aligned frags)
#define XSTR 68           // xs row stride (fp32)
#define CSTR 132          // C buffer row stride (fp32)
#define BFRAG_ELEMS (NKT * 8 * 64 * 8)   // 270336 f16
#define LOG2E 1.4426950408889634f
#define INV2PI 0.15915494309189535f

// ws float-offsets (after 270336 f16 = 135168 floats of Bfrag)
#define OFF_WP 135168     // [256]  log2e-folded WP[4][64]
#define OFF_CP 135424     // [4]
#define OFF_FV 135680     // 1024 halves (512 floats): fp16 fm*fs
#define OFF_PH 136192     // 1024 halves: fp16 phase/2pi
#define OFF_MX 136704     // [128]  per-d {max,min} of fp16-rounded fv

typedef __attribute__((ext_vector_type(4))) float f32x4;
typedef __attribute__((ext_vector_type(8))) _Float16 f16x8;
typedef __attribute__((ext_vector_type(2))) __fp16 fp16v2;   // builtin's return type

__device__ __forceinline__ unsigned pkh(float a, float b) {
#if __has_builtin(__builtin_amdgcn_cvt_pkrtz)
    union { fp16v2 h; unsigned u; } r;
    r.h = __builtin_amdgcn_cvt_pkrtz(a, b);     // 1 op: v_cvt_pkrtz_f16_f32
    return r.u;
#else
    union { _Float16 h[2]; unsigned u; } r;
    r.h[0] = (_Float16)a; r.h[1] = (_Float16)b;
    return r.u;
#endif
}

#if __has_builtin(__builtin_amdgcn_exp2f)
#define EXP2(x) __builtin_amdgcn_exp2f(x)
#else
#define EXP2(x) exp2f(x)
#endif
#if __has_builtin(__builtin_amdgcn_rcpf)
#define RCP(x) __builtin_amdgcn_rcpf(x)
#else
#define RCP(x) (1.0f / (x))
#endif
#if __has_builtin(__builtin_amdgcn_sinf)
#define SINR(x) __builtin_amdgcn_sinf(x)   // sin(2*pi*x), revolutions (verified R3-R12)
#define COSR(x) __builtin_amdgcn_cosf(x)
#else
#define SINR(x) __sinf(6.283185307179586f * (x))
#define COSR(x) __cosf(6.283185307179586f * (x))
#endif

// ---------------- precompute: pack B fragment-major f16, fold attention, stage fv/ph (fp16) ----------------
__global__ __launch_bounds__(256) void aff_pre(
    const float* __restrict__ Wq, const float* __restrict__ bq,
    const float* __restrict__ Wk1,
    const float* __restrict__ Wqi, const float* __restrict__ bqi,
    const float* __restrict__ Wki,
    const float* __restrict__ Wg, const float* __restrict__ Wp,
    const float* __restrict__ fm, const float* __restrict__ fs,
    const float* __restrict__ phase,
    float* __restrict__ ws)
{
    _Float16* Bf = (_Float16*)ws;
    const int tid = threadIdx.x;
    const int gid = blockIdx.x * 256 + tid;   // < 270336 exactly

    {
        int j  = gid & 7;
        int q  = (gid >> 3) & 3;
        int nl = (gid >> 5) & 15;
        int nt = (gid >> 9) & 7;
        int kt = gid >> 12;
        int k = kt * 32 + q * 8 + j;
        int n = nt * 16 + nl;
        float s = (n < 64) ? Wg[(size_t)n * DIN + k] : Wp[(size_t)(n - 64) * DIN + k];
        int dst = ((kt * 8 + nt) * 64 + q * 16 + nl) * 8 + j;
        Bf[dst] = (_Float16)s;
    }

    if (blockIdx.x == 0) {
        float* WP = ws + OFF_WP;
        float* cP = ws + OFF_CP;
        unsigned* fvh = (unsigned*)(ws + OFF_FV);
        unsigned* phh = (unsigned*)(ws + OFF_PH);
        float* mxg = ws + OFF_MX;

        {
            float4 a = ((const float4*)fm)[tid];
            float4 b = ((const float4*)fs)[tid];
            fvh[tid * 2]     = pkh(a.x * b.x, a.y * b.y);
            fvh[tid * 2 + 1] = pkh(a.z * b.z, a.w * b.w);
            float4 p = ((const float4*)phase)[tid];
            phh[tid * 2]     = pkh(p.x * INV2PI, p.y * INV2PI);
            phh[tid * 2 + 1] = pkh(p.z * INV2PI, p.w * INV2PI);
        }
        if (tid < 64) {
            float mx = -1e30f, mn = 1e30f;
            #pragma unroll
            for (int f = 0; f < 16; ++f) {
                float v = (float)(_Float16)(fm[tid * 16 + f] * fs[tid * 16 + f]);  // fp16-rounded
                mx = fmaxf(mx, v); mn = fminf(mn, v);
            }
            mxg[tid * 2] = mx; mxg[tid * 2 + 1] = mn;
        }

        __shared__ float u[32];
        if (tid < 32) {
            float s = 0.f;
            #pragma unroll
            for (int a = 0; a < 32; ++a) s += Wki[tid * 32 + a] * Wk1[a];
            u[tid] = s;
        }
        __syncthreads();
        {
            const int h = tid >> 6;
            const int d = tid & 63;
            float s = 0.f;
            for (int j = 0; j < 8; ++j) {
                int e = h * 8 + j;
                float wc = 0.f;
                #pragma unroll
                for (int a = 0; a < 32; ++a) wc += Wqi[e * 32 + a] * Wq[a * 64 + d];
                s += u[e] * wc;
            }
            WP[h * 64 + d] = s * 0.35355339059327373f * LOG2E;
            if (d == 0) {
                float sc = 0.f;
                for (int j = 0; j < 8; ++j) {
                    int e = h * 8 + j;
                    float bcv = bqi[e];
                    #pragma unroll
                    for (int a = 0; a < 32; ++a) bcv += Wqi[e * 32 + a] * bq[a];
                    sc += u[e] * bcv;
                }
                cP[h] = sc * 0.35355339059327373f * LOG2E;
            }
        }
    }
}

// ---------------- main fused kernel (R10 best-measured variant) ----------------
// 16 tokens/block, 256 threads = 4 waves. Wave w: n-tiles {2w, 2w+1}, single m-tile (16 tok).
// Per-chunk pipeline: MFMA(ch) [B-frags loaded one build ago -> stall-free] ;
// issue all 16 B loads for ch+1 ; build(ch+1) [~600+ cyc, hides L2 latency] ; barrier.
__global__ __launch_bounds__(NTHR, 3) void aff_main(
    const float* __restrict__ x,
    const float* __restrict__ ws_c,
    const float* __restrict__ bg, const float* __restrict__ bp,
    float* __restrict__ out)
{
    __shared__ __align__(16) float xs[TOK * XSTR];           // 4352 B
    __shared__ __align__(16) _Float16 Ab[2][TOK * ASTR];     // 2 x 8448 B
    __shared__ __align__(16) float Pl[TOK * 4];              // 256 B
    __shared__ __align__(16) _Float16 fvh[1024];             // 2048 B
    __shared__ __align__(16) _Float16 phh[1024];             // 2048 B
    __shared__ __align__(16) float mxs[128];                 // 512 B

    const f16x8* Bv = (const f16x8*)ws_c;
    const float* WP  = ws_c + OFF_WP;
    const float* cP  = ws_c + OFF_CP;
    const float* mxg = ws_c + OFF_MX;

    const int tid  = threadIdx.x;
    const int lane = tid & 63;
    const int w    = tid >> 6;          // wave 0..3
    const int t0   = blockIdx.x * TOK;
    const int lm   = lane & 15;
    const int lq   = lane >> 4;
    const int fh   = lq & 1;
    const int dsel = lane >> 5;
    const int dloc = (w << 1) + dsel;   // 0..7 within chunk

    // ---- stage: fv/ph (fp16), minmax, x -> LDS ----
    {
        uint2 fv2 = ((const uint2*)(ws_c + OFF_FV))[tid];
        uint2 ph2 = ((const uint2*)(ws_c + OFF_PH))[tid];
        ((uint2*)fvh)[tid] = fv2;
        ((uint2*)phh)[tid] = ph2;
    }
    if (tid < 32) ((float4*)mxs)[tid] = ((const float4*)mxg)[tid];
    {
        int t = tid >> 4, j4 = (tid & 15) * 4;
        float4 xv = *(const float4*)(x + (size_t)(t0 + t) * 64 + j4);
        *(float4*)(xs + t * XSTR + j4) = xv;
    }
    __syncthreads();

    // ---- P (exp2-domain): 128 threads, split-d halves, shfl combine ----
    if (tid < 128) {
        int t = tid & 15, dh = (tid >> 4) & 1, h = tid >> 5;
        float acc = 0.f;
        const float* wp = WP + h * 64 + dh * 32;
        const float* xr = xs + t * XSTR + dh * 32;
        #pragma unroll 8
        for (int d = 0; d < 32; ++d) acc = fmaf(wp[d], xr[d], acc);
        acc += __shfl_xor(acc, 16);
        if (dh == 0) Pl[t * 4 + h] = acc + cP[h];
    }

    f32x4 acc0 = {}, acc1 = {};
    const f16x8* Bw0 = Bv + (size_t)(2 * w) * 64 + lane;       // n-tile 2w base
    const f16x8* Bw1 = Bv + (size_t)(2 * w + 1) * 64 + lane;   // n-tile 2w+1 base

    // ---- x part (kt 0,1), f16 conversion on the fly ----
    #pragma unroll
    for (int ks = 0; ks < 2; ++ks) {
        f16x8 b0 = Bw0[(size_t)ks * 512];
        f16x8 b1 = Bw1[(size_t)ks * 512];
        const float* xr = xs + lm * XSTR + ks * 32 + lq * 8;
        float4 fa = *(const float4*)xr;
        float4 fb = *(const float4*)(xr + 4);
        union { unsigned u[4]; f16x8 v; } av;
        av.u[0] = pkh(fa.x, fa.y); av.u[1] = pkh(fa.z, fa.w);
        av.u[2] = pkh(fb.x, fb.y); av.u[3] = pkh(fb.z, fb.w);
        acc0 = __builtin_amdgcn_mfma_f32_16x16x32_f16(av.v, b0, acc0, 0, 0, 0);
        acc1 = __builtin_amdgcn_mfma_f32_16x16x32_f16(av.v, b1, acc1, 0, 0, 0);
    }
    __syncthreads();   // Pl ready

    const float w2 = (float)((t0 + lm) & (SS - 1)) * (1.0f / 2047.0f);  // revolutions

    // hoisted build pointers (advance by fixed strides per chunk)
    const _Float16* fvp0 = fvh + dloc * 16 + fh * 8;
    const _Float16* php0 = phh + dloc * 16 + fh * 8;
    const float* mxp0 = mxs + dloc * 2;
    _Float16* dst0 = &Ab[0][lm * ASTR + dloc * 32 + fh * 8];
    _Float16* dst1 = &Ab[1][lm * ASTR + dloc * 32 + fh * 8];

    auto build = [&](int ch, _Float16* dst) {
        union { uint4 q; _Float16 h[8]; } fu, pu;
        fu.q = *(const uint4*)(fvp0 + ch * 128);
        pu.q = *(const uint4*)(php0 + ch * 128);
        const float4 Pv = *(const float4*)(Pl + lm * 4);
        const float mxv = mxp0[ch * 16], mnv = mxp0[ch * 16 + 1];
        float fl[8], pr[8];
        #pragma unroll
        for (int j = 0; j < 8; ++j) { fl[j] = (float)fu.h[j]; pr[j] = (float)pu.h[j]; }
        float aw[8] = {0.f, 0.f, 0.f, 0.f, 0.f, 0.f, 0.f, 0.f};
        float Ph4[4] = {Pv.x, Pv.y, Pv.z, Pv.w};
        #pragma unroll
        for (int h = 0; h < 4; ++h) {
            float Ph = Ph4[h];
            float m = fmaxf(mxv * Ph, mnv * Ph);   // exact row max (monotone in f)
            float e[8]; float s = 0.f;
            #pragma unroll
            for (int j = 0; j < 8; ++j) { e[j] = EXP2(fmaf(fl[j], Ph, -m)); s += e[j]; }
            float z = s + __shfl_xor(s, 16);       // other f-half
            float inv = 0.25f * RCP(z);            // head-mean folded
            #pragma unroll
            for (int j = 0; j < 8; ++j) aw[j] = fmaf(e[j], inv, aw[j]);
        }
        unsigned sv[4], cv[4];
        #pragma unroll
        for (int jp = 0; jp < 4; ++jp) {
            int j0 = 2 * jp;
            float X0 = fmaf(w2, fl[j0], pr[j0]);
            float X1 = fmaf(w2, fl[j0 + 1], pr[j0 + 1]);
            float a0 = aw[j0], a1 = aw[j0 + 1];
            sv[jp] = pkh(a0 * SINR(X0), a1 * SINR(X1));
            cv[jp] = pkh(a0 * COSR(X0), a1 * COSR(X1));
        }
        uint4 v0; v0.x = sv[0]; v0.y = sv[1]; v0.z = sv[2]; v0.w = sv[3];
        uint4 v1; v1.x = cv[0]; v1.y = cv[1]; v1.z = cv[2]; v1.w = cv[3];
        *(uint4*)dst = v0;
        *(uint4*)(dst + 16) = v1;
    };

    // ---- batched B prefetch: all 16 fragments of a chunk in one burst ----
    f16x8 bf[16];
    auto loadB = [&](int ch) {
        const size_t base = (size_t)(2 + ch * 8) * 512;
        #pragma unroll
        for (int ks = 0; ks < 8; ++ks) {
            bf[2 * ks]     = Bw0[base + ks * 512];
            bf[2 * ks + 1] = Bw1[base + ks * 512];
        }
    };

    // prologue: issue chunk-0 loads, build chunk 0 under them
    loadB(0);
    build(0, dst0);
    __syncthreads();

    // ---- pipelined K loop ----
    for (int ch = 0; ch < 8; ++ch) {
        const _Float16* Ar = &Ab[ch & 1][0];
        // MFMA phase: B frags have been in flight for a full build+barrier
        #pragma unroll
        for (int ks = 0; ks < 8; ++ks) {
            f16x8 a = *(const f16x8*)(Ar + lm * ASTR + ks * 32 + lq * 8);
            acc0 = __builtin_amdgcn_mfma_f32_16x16x32_f16(a, bf[2 * ks], acc0, 0, 0, 0);
            acc1 = __builtin_amdgcn_mfma_f32_16x16x32_f16(a, bf[2 * ks + 1], acc1, 0, 0, 0);
        }
        if (ch < 7) {
            loadB(ch + 1);                       // issue next chunk's 16 loads
            build(ch + 1, (ch & 1) ? dst0 : dst1);  // ~600+ cyc: hides their latency
        }
        __syncthreads();
    }

    // ---- epilogue ----
    float* Cb = (float*)(&Ab[0][0]);   // 16*132*4 = 8448 B, fits Ab[0]
    #pragma unroll
    for (int r = 0; r < 4; ++r) {
        Cb[(lq * 4 + r) * CSTR + (2 * w) * 16 + lm]     = acc0[r];
        Cb[(lq * 4 + r) * CSTR + (2 * w + 1) * 16 + lm] = acc1[r];
    }
    __syncthreads();
    {
        int t = tid >> 4, o0 = (tid & 15) * 4;
        float4 g4 = *(float4*)(Cb + t * CSTR + o0);
        float4 p4 = *(float4*)(Cb + t * CSTR + 64 + o0);
        float4 bg4 = *(const float4*)(bg + o0);
        float4 bp4 = *(const float4*)(bp + o0);
        float4 xr = *(float4*)(xs + t * XSTR + o0);
        float4 o;
        { float g = g4.x + bg4.x, p = p4.x + bp4.x;
          float sg = RCP(1.f + EXP2(-g * LOG2E));
          float sp = RCP(1.f + EXP2(-p * LOG2E));
          o.x = fmaf(p * sg, sp, xr.x); }
        { float g = g4.y + bg4.y, p = p4.y + bp4.y;
          float sg = RCP(1.f + EXP2(-g * LOG2E));
          float sp = RCP(1.f + EXP2(-p * LOG2E));
          o.y = fmaf(p * sg, sp, xr.y); }
        { float g = g4.z + bg4.z, p = p4.z + bp4.z;
          float sg = RCP(1.f + EXP2(-g * LOG2E));
          float sp = RCP(1.f + EXP2(-p * LOG2E));
          o.z = fmaf(p * sg, sp, xr.z); }
        { float g = g4.w + bg4.w, p = p4.w + bp4.w;
          float sg = RCP(1.f + EXP2(-g * LOG2E));
          float sp = RCP(1.f + EXP2(-p * LOG2E));
          o.w = fmaf(p * sg, sp, xr.w); }
        *(float4*)(out + (size_t)(t0 + t) * 64 + o0) = o;
    }
}

extern "C" void kernel_launch(void* const* d_in, const int* in_sizes, int n_in,
                              void* d_out, int out_size, void* d_ws, size_t ws_size,
                              hipStream_t stream) {
    (void)in_sizes; (void)n_in; (void)out_size; (void)ws_size;
    const float* x    = (const float*)d_in[0];
    const float* fm   = (const float*)d_in[1];
    const float* phs  = (const float*)d_in[2];
    const float* fs   = (const float*)d_in[3];
    const float* Wq   = (const float*)d_in[4];
    const float* bq   = (const float*)d_in[5];
    const float* Wk1  = (const float*)d_in[6];
    // d_in[7] = bk1: cancels in softmax
    const float* Wqi  = (const float*)d_in[8];
    const float* bqi  = (const float*)d_in[9];
    const float* Wki  = (const float*)d_in[10];
    // d_in[11] = bki: cancels in softmax
    const float* Wg   = (const float*)d_in[12];
    const float* bg   = (const float*)d_in[13];
    const float* Wp   = (const float*)d_in[14];
    const float* bp   = (const float*)d_in[15];
    float* out = (float*)d_out;
    float* ws  = (float*)d_ws;

    aff_pre<<<BFRAG_ELEMS / 256, 256, 0, stream>>>(Wq, bq, Wk1, Wqi, bqi, Wki, Wg, Wp,
                                                   fm, fs, phs, ws);
    aff_main<<<NBLK, NTHR, 0, stream>>>(x, (const float*)ws, bg, bp, out);
}